// Round 9
// baseline (385.293 us; speedup 1.0000x reference)
//
#include <hip/hip_runtime.h>
#include <hip/hip_bf16.h>

// EdgeConvUp — N_REF=50000, N_Q=25000, E=400000, C=128, MLP 128/256/256. fp32 in/out.

#define N_REF 50000
#define N_Q   25000
#define E_CNT 400000
#define C0    128
#define C1N   256
#define C2N   256
#define BN_EPS 1e-5f
#define CAP   96        // bucket slots per query (mean deg 16, std 4; 96 = 20 sigma)
#define CNTS  16        // cnt stride (ints) -> one counter per 64B L2 line
#define LDSS  72        // LDS row stride (64 + 8 pad) in bf16 elements
#define NB_BK 196       // bucket role blocks in mega1
#define NB_G1 391       // ceil(50000/128)
#define NB_G3 196       // ceil(25000/128)

typedef __bf16 bf16x8 __attribute__((ext_vector_type(8)));
typedef float  f32x4  __attribute__((ext_vector_type(4)));

// ---------- weight convert+transpose + zero counters/accumulators/tickets ----------
__global__ __launch_bounds__(256) void convT_all(
    const float* __restrict__ Wf0, const float* __restrict__ Ws0,
    const float* __restrict__ W1,  const float* __restrict__ W2,
    __bf16* __restrict__ Wf0t, __bf16* __restrict__ Ws0t,
    __bf16* __restrict__ W1t,  __bf16* __restrict__ W2t,
    int* __restrict__ zero_base, int zero_n)
{
    __shared__ float t[32][33];
    int b = blockIdx.x;
    for (int i = b * 256 + threadIdx.x; i < zero_n; i += 128 * 256) zero_base[i] = 0;
    const float* W; __bf16* O; int K, N, lb;
    if (b < 16)      { W = Wf0; O = Wf0t; K = 128; N = 128; lb = b; }
    else if (b < 32) { W = Ws0; O = Ws0t; K = 128; N = 128; lb = b - 16; }
    else if (b < 64) { W = W1;  O = W1t;  K = 128; N = 256; lb = b - 32; }
    else             { W = W2;  O = W2t;  K = 256; N = 256; lb = b - 64; }
    int nkb = K / 32;
    int bk = (lb % nkb) * 32, bn = (lb / nkb) * 32;
    int tx = threadIdx.x & 31, ty = threadIdx.x >> 5;
    #pragma unroll
    for (int i = 0; i < 32; i += 8)
        t[ty + i][tx] = W[(size_t)(bk + ty + i) * N + bn + tx];
    __syncthreads();
    #pragma unroll
    for (int i = 0; i < 32; i += 8)
        O[(size_t)(bn + ty + i) * K + bk + tx] = (__bf16)t[tx][ty + i];
}

__device__ inline void loadA8(const float* p, float* v) {
    float4 a0 = *(const float4*)p, a1 = *(const float4*)(p + 4);
    v[0] = a0.x; v[1] = a0.y; v[2] = a0.z; v[3] = a0.w;
    v[4] = a1.x; v[5] = a1.y; v[6] = a1.z; v[7] = a1.w;
}
__device__ inline void loadA8(const __bf16* p, float* v) {
    bf16x8 a = *(const bf16x8*)p;
    #pragma unroll
    for (int j = 0; j < 8; j++) v[j] = (float)a[j];
}

// ---------- GEMM body: 128x128 tile, BK=64, fused A-transform, bias, fused BN finalize --
// AMODE: 0 plain; 1 relu(a*s+t); 2 relu(a + y*s + t). Output bf16.
// Epilogue: per-block col sums -> global atomics; last block (ticket) computes s/t.
template <typename TA, int AMODE>
__device__ __forceinline__ void gemm_dev(
    __bf16* As, __bf16* Bs, float* sLDS, float* qLDS,
    const TA* __restrict__ A, const TA* __restrict__ A2,
    const float* __restrict__ sA, const float* __restrict__ tA,
    const __bf16* __restrict__ Bt, const float* __restrict__ bias,
    __bf16* __restrict__ Ch,
    float* __restrict__ SUM, float* __restrict__ SQ,
    const float* __restrict__ gam, const float* __restrict__ bet,
    float* __restrict__ sfin, float* __restrict__ tfin,
    float invM, int* __restrict__ ticket, int nblk,
    int M, int N, int K, int bx, int by)
{
    const int bm = bx * 128, bn = by * 128;
    const int tid = threadIdx.x;
    const int wave = tid >> 6, lane = tid & 63;
    const int wm = wave >> 1, wn = wave & 1;
    const int m = lane & 15, quad = lane >> 4;
    f32x4 acc[4][4] = {};

    for (int kt = 0; kt < K; kt += 64) {
        #pragma unroll
        for (int cc = 0; cc < 4; cc++) {
            int c = tid + cc * 256;
            int row = c >> 3, kofs = (c & 7) * 8;
            int gr = bm + row;
            float va[8] = {0.f, 0.f, 0.f, 0.f, 0.f, 0.f, 0.f, 0.f};
            if (gr < M) {
                loadA8(A + (size_t)gr * K + kt + kofs, va);
                if (AMODE == 1) {
                    #pragma unroll
                    for (int j = 0; j < 8; j++)
                        va[j] = fmaxf(va[j] * sA[kt + kofs + j] + tA[kt + kofs + j], 0.f);
                } else if (AMODE == 2) {
                    float vy[8];
                    loadA8(A2 + (size_t)gr * K + kt + kofs, vy);
                    #pragma unroll
                    for (int j = 0; j < 8; j++)
                        va[j] = fmaxf(va[j] + vy[j] * sA[kt + kofs + j] + tA[kt + kofs + j], 0.f);
                }
            }
            bf16x8 av;
            #pragma unroll
            for (int j = 0; j < 8; j++) av[j] = (__bf16)va[j];
            *(bf16x8*)(As + row * LDSS + kofs) = av;
        }
        #pragma unroll
        for (int cc = 0; cc < 4; cc++) {
            int c = tid + cc * 256;
            int row = c >> 3, kofs = (c & 7) * 8;
            *(float4*)(Bs + row * LDSS + kofs) =
                *(const float4*)(Bt + (size_t)(bn + row) * K + kt + kofs);
        }
        __syncthreads();

        #pragma unroll
        for (int ks = 0; ks < 64; ks += 32) {
            bf16x8 af[4], bfr[4];
            #pragma unroll
            for (int mt = 0; mt < 4; mt++)
                af[mt] = *(const bf16x8*)(As + (wm * 64 + mt * 16 + m) * LDSS + ks + quad * 8);
            #pragma unroll
            for (int nt = 0; nt < 4; nt++)
                bfr[nt] = *(const bf16x8*)(Bs + (wn * 64 + nt * 16 + m) * LDSS + ks + quad * 8);
            #pragma unroll
            for (int mt = 0; mt < 4; mt++)
                #pragma unroll
                for (int nt = 0; nt < 4; nt++)
                    acc[mt][nt] = __builtin_amdgcn_mfma_f32_16x16x32_bf16(af[mt], bfr[nt], acc[mt][nt], 0, 0, 0);
        }
        __syncthreads();
    }

    if (tid < 128) { sLDS[tid] = 0.f; qLDS[tid] = 0.f; }
    __syncthreads();
    #pragma unroll
    for (int nt = 0; nt < 4; nt++) {
        int lcol = wn * 64 + nt * 16 + m;
        int col = bn + lcol;
        float bv = bias ? bias[col] : 0.f;
        float s_part = 0.f, q_part = 0.f;
        #pragma unroll
        for (int mt = 0; mt < 4; mt++) {
            #pragma unroll
            for (int r = 0; r < 4; r++) {
                int row = bm + wm * 64 + mt * 16 + quad * 4 + r;
                float v = acc[mt][nt][r] + bv;
                bool ok = row < M;
                s_part += ok ? v : 0.f;
                q_part += ok ? v * v : 0.f;
                if (ok) Ch[(size_t)row * N + col] = (__bf16)v;
            }
        }
        s_part += __shfl_xor(s_part, 16); s_part += __shfl_xor(s_part, 32);
        q_part += __shfl_xor(q_part, 16); q_part += __shfl_xor(q_part, 32);
        if (quad == 0) {
            atomicAdd(&sLDS[lcol], s_part);
            atomicAdd(&qLDS[lcol], q_part);
        }
    }
    __syncthreads();
    if (tid < 128) {
        atomicAdd(&SUM[bn + tid], sLDS[tid]);
        atomicAdd(&SQ[bn + tid], qLDS[tid]);
    }
    // ticket: last block of this GEMM finalizes BN scale/shift
    __threadfence();
    __shared__ int lastFlag;
    if (tid == 0) lastFlag = (atomicAdd(ticket, 1) == nblk - 1) ? 1 : 0;
    __syncthreads();
    if (lastFlag) {
        for (int c = tid; c < N; c += 256) {
            float s = atomicAdd(&SUM[c], 0.f);   // atomic read (coherent point)
            float q = atomicAdd(&SQ[c], 0.f);
            float mu = s * invM;
            float var = q * invM - mu * mu;
            float sc = gam[c] * rsqrtf(var + BN_EPS);
            sfin[c] = sc;
            tfin[c] = bet[c] - mu * sc;
        }
    }
}

// ---------- bucket body: edge -> (q, slot), padded counters ----------
__device__ __forceinline__ void bucket_dev(
    const float* __restrict__ ref_bxyz, const float* __restrict__ query_bxyz,
    const int* __restrict__ e_ref, const int* __restrict__ e_query,
    int* __restrict__ cnt, int2* __restrict__ bp, int bkIdx)
{
    for (int e = bkIdx * 256 + threadIdx.x; e < E_CNT; e += NB_BK * 256) {
        int r = e_ref[e], q = e_query[e];
        float4 rp = *(const float4*)(ref_bxyz + (size_t)r * 4);
        float4 qp = *(const float4*)(query_bxyz + (size_t)q * 4);
        float dx = rp.y - qp.y, dy = rp.z - qp.z, dz = rp.w - qp.w;
        float wv = 1.f / (sqrtf(dx * dx + dy * dy + dz * dz) + 1e-8f);
        int pos = atomicAdd(&cnt[q * CNTS], 1);
        if (pos < CAP) bp[(size_t)q * CAP + pos] = make_int2(r, __float_as_int(wv));
    }
}

// ---------- mega1: bucket (196) + gemm1 (391) + gemm3 (196) ----------
__global__ __launch_bounds__(256) void mega1(
    const float* __restrict__ ref_feat, const float* __restrict__ query_feat,
    const __bf16* __restrict__ Wf0t, const __bf16* __restrict__ Ws0t,
    __bf16* __restrict__ C1h, __bf16* __restrict__ C2b,
    float* __restrict__ SUM0, float* __restrict__ SQ0,
    float* __restrict__ SUM1, float* __restrict__ SQ1,
    const float* __restrict__ gf0, const float* __restrict__ bf0,
    const float* __restrict__ gs0, const float* __restrict__ bs0,
    float* __restrict__ s0, float* __restrict__ t0,
    float* __restrict__ s1, float* __restrict__ t1,
    int* __restrict__ T0, int* __restrict__ T1,
    const float* __restrict__ ref_bxyz, const float* __restrict__ query_bxyz,
    const int* __restrict__ e_ref, const int* __restrict__ e_query,
    int* __restrict__ cnt, int2* __restrict__ bp)
{
    __shared__ __align__(16) __bf16 As[128 * LDSS];
    __shared__ __align__(16) __bf16 Bs[128 * LDSS];
    __shared__ float sLDS[128], qLDS[128];
    int b = blockIdx.x;
    if (b < NB_BK) {
        bucket_dev(ref_bxyz, query_bxyz, e_ref, e_query, cnt, bp, b);
    } else if (b < NB_BK + NB_G1) {
        gemm_dev<float, 0>(As, Bs, sLDS, qLDS, ref_feat, nullptr, nullptr, nullptr,
                           Wf0t, nullptr, C1h, SUM0, SQ0, gf0, bf0, s0, t0,
                           1.f / N_REF, T0, NB_G1, N_REF, C0, C0, b - NB_BK, 0);
    } else {
        gemm_dev<float, 0>(As, Bs, sLDS, qLDS, query_feat, nullptr, nullptr, nullptr,
                           Ws0t, nullptr, C2b, SUM1, SQ1, gs0, bs0, s1, t1,
                           1.f / N_Q, T1, NB_G3, N_Q, C0, C0, b - NB_BK - NB_G1, 0);
    }
}

// ---------- standalone GEMM (g4/g5) ----------
template <typename TA, int AMODE>
__global__ __launch_bounds__(256) void gemm_mfma(
    const TA* __restrict__ A, const TA* __restrict__ A2,
    const float* __restrict__ sA, const float* __restrict__ tA,
    const __bf16* __restrict__ Bt, const float* __restrict__ bias,
    __bf16* __restrict__ Ch,
    float* __restrict__ SUM, float* __restrict__ SQ,
    const float* __restrict__ gam, const float* __restrict__ bet,
    float* __restrict__ sfin, float* __restrict__ tfin,
    float invM, int* __restrict__ ticket,
    int M, int N, int K)
{
    __shared__ __align__(16) __bf16 As[128 * LDSS];
    __shared__ __align__(16) __bf16 Bs[128 * LDSS];
    __shared__ float sLDS[128], qLDS[128];
    gemm_dev<TA, AMODE>(As, Bs, sLDS, qLDS, A, A2, sA, tA, Bt, bias, Ch,
                        SUM, SQ, gam, bet, sfin, tfin, invM, ticket,
                        gridDim.x * gridDim.y, M, N, K, blockIdx.x, blockIdx.y);
}

// ---------- gather (standalone, 0 LDS, high occupancy): wave/query, 4-edge ILP ----------
__global__ __launch_bounds__(256) void gather_kernel(
    const __bf16* __restrict__ C1h, const float* __restrict__ s0, const float* __restrict__ t0,
    const int* __restrict__ cnt, const int2* __restrict__ bp,
    __bf16* __restrict__ qf, int NQ)
{
    int q = blockIdx.x * 4 + (threadIdx.x >> 6);
    if (q >= NQ) return;
    int lane = threadIdx.x & 63;
    int sub = lane >> 4, m = lane & 15;
    int deg = min(cnt[q * CNTS], CAP);
    const int base = q * CAP;
    float acc[8] = {};
    float ws = 0.f;
    int i = sub;
    for (; i + 4 < deg; i += 8) {
        int2 p0 = bp[base + i], p1 = bp[base + i + 4];
        float w0 = __int_as_float(p0.y), w1 = __int_as_float(p1.y);
        bf16x8 v0 = *(const bf16x8*)(C1h + (size_t)p0.x * C0 + m * 8);
        bf16x8 v1 = *(const bf16x8*)(C1h + (size_t)p1.x * C0 + m * 8);
        ws += w0 + w1;
        #pragma unroll
        for (int j = 0; j < 8; j++) acc[j] += (float)v0[j] * w0 + (float)v1[j] * w1;
    }
    if (i < deg) {
        int2 p0 = bp[base + i];
        float w0 = __int_as_float(p0.y);
        bf16x8 v0 = *(const bf16x8*)(C1h + (size_t)p0.x * C0 + m * 8);
        ws += w0;
        #pragma unroll
        for (int j = 0; j < 8; j++) acc[j] += (float)v0[j] * w0;
    }
    ws += __shfl_xor(ws, 16); ws += __shfl_xor(ws, 32);
    #pragma unroll
    for (int j = 0; j < 8; j++) {
        acc[j] += __shfl_xor(acc[j], 16);
        acc[j] += __shfl_xor(acc[j], 32);
    }
    if (sub == 0) {
        float inv = (deg > 0) ? 1.f / ws : 0.f;
        float has = (deg > 0) ? 1.f : 0.f;
        bf16x8 o;
        #pragma unroll
        for (int j = 0; j < 8; j++) {
            int ch = m * 8 + j;
            o[j] = (__bf16)(acc[j] * inv * s0[ch] + t0[ch] * has);
        }
        *(bf16x8*)(qf + (size_t)q * C0 + m * 8) = o;
    }
}

// ---------- final: out = relu(bn(h2)), h2 bf16 -> out fp32, 8 elems/thread ----------
__global__ __launch_bounds__(256) void final_kernel(
    const __bf16* __restrict__ h2, const float* __restrict__ s, const float* __restrict__ t,
    float* __restrict__ out, int n8)
{
    int i8 = blockIdx.x * 256 + threadIdx.x;
    if (i8 >= n8) return;
    int base = i8 * 8;
    int c = base & 255;
    bf16x8 h = *(const bf16x8*)(h2 + base);
    float o[8];
    #pragma unroll
    for (int j = 0; j < 8; j++) {
        float v = (float)h[j] * s[c + j] + t[c + j];
        o[j] = v > 0.f ? v : 0.f;
    }
    *(float4*)(out + base)     = make_float4(o[0], o[1], o[2], o[3]);
    *(float4*)(out + base + 4) = make_float4(o[4], o[5], o[6], o[7]);
}

extern "C" void kernel_launch(void* const* d_in, const int* in_sizes, int n_in,
                              void* d_out, int out_size, void* d_ws, size_t ws_size,
                              hipStream_t stream)
{
    const float* ref_bxyz   = (const float*)d_in[0];
    const float* ref_feat   = (const float*)d_in[1];
    const float* query_bxyz = (const float*)d_in[2];
    const float* query_feat = (const float*)d_in[3];
    const int* e_ref   = (const int*)d_in[4];
    const int* e_query = (const int*)d_in[5];
    const float* Wf0 = (const float*)d_in[6];
    const float* gf0 = (const float*)d_in[7];
    const float* bf0 = (const float*)d_in[8];
    const float* Ws0 = (const float*)d_in[9];
    const float* gs0 = (const float*)d_in[10];
    const float* bs0 = (const float*)d_in[11];
    const float* W1  = (const float*)d_in[12];
    const float* b1  = (const float*)d_in[13];
    const float* g1  = (const float*)d_in[14];
    const float* be1 = (const float*)d_in[15];
    const float* W2  = (const float*)d_in[16];
    const float* b2  = (const float*)d_in[17];
    const float* g2  = (const float*)d_in[18];
    const float* be2 = (const float*)d_in[19];
    float* out = (float*)d_out;

    char* ws = (char*)d_ws;
    const size_t MB = 1024 * 1024;
    const size_t OFF_C1 = 0;              // C1 bf16 [50000,128] 12.8MB
    const size_t OFF_QF = 13 * MB;        // QF bf16 [25000,128] 6.4MB
    const size_t OFF_C2 = 20 * MB;        // C2 bf16 [25000,128] 6.4MB
    const size_t OFF_H1 = 27 * MB;        // h1 bf16 [25000,256] 12.8MB
    const size_t OFF_H2 = 40 * MB;        // h2 bf16 [25000,256] 12.8MB
    const size_t OFF_BP = 53 * MB;        // packed buckets int2 [25000*96] 19.2MB
    const size_t OFF_CNT = 73 * MB;       // padded cnt [25000*16] + ACC + tickets
    const size_t OFF_ST = 77 * MB;        // s/t arrays
    const size_t OFF_BT = OFF_ST + 16384; // bf16 weights 256KB
    __bf16* C1h = (__bf16*)(ws + OFF_C1);
    __bf16* QF  = (__bf16*)(ws + OFF_QF);
    __bf16* C2b = (__bf16*)(ws + OFF_C2);
    __bf16* H1  = (__bf16*)(ws + OFF_H1);
    __bf16* H2  = (__bf16*)(ws + OFF_H2);
    int2*   BP  = (int2*)(ws + OFF_BP);
    int*    CNT = (int*)(ws + OFF_CNT);
    float*  ACC = (float*)(CNT + N_Q * CNTS);     // 2048 floats: SUM/SQ x4 layers
    int*    TK  = (int*)(ACC + 2048);             // 4 tickets
    const int ZERO_N = N_Q * CNTS + 2048 + 4;
    float *SUM0 = ACC,        *SQ0 = ACC + 256;
    float *SUM1 = ACC + 512,  *SQ1 = ACC + 768;
    float *SUM2 = ACC + 1024, *SQ2 = ACC + 1280;
    float *SUM3 = ACC + 1536, *SQ3 = ACC + 1792;
    float* ST = (float*)(ws + OFF_ST);
    float *s0 = ST,        *t0 = ST + 256;
    float *s1 = ST + 512,  *t1 = ST + 768;
    float *s2 = ST + 1024, *t2 = ST + 1280;
    float *s3 = ST + 1536, *t3 = ST + 1792;
    __bf16* Wf0t = (__bf16*)(ws + OFF_BT);
    __bf16* Ws0t = Wf0t + 128 * 128;
    __bf16* W1t  = Ws0t + 128 * 128;
    __bf16* W2t  = W1t + 256 * 128;

    // 0) weight conversion + zero cnt/accumulators/tickets
    convT_all<<<128, 256, 0, stream>>>(Wf0, Ws0, W1, W2, Wf0t, Ws0t, W1t, W2t, CNT, ZERO_N);

    // 1) fused: bucket + C1 = ref_feat@Wf0 + C2 = query_feat@Ws0 (BN finalize fused)
    mega1<<<NB_BK + NB_G1 + NB_G3, 256, 0, stream>>>(
        ref_feat, query_feat, Wf0t, Ws0t, C1h, C2b,
        SUM0, SQ0, SUM1, SQ1, gf0, bf0, gs0, bs0, s0, t0, s1, t1, TK + 0, TK + 1,
        ref_bxyz, query_bxyz, e_ref, e_query, CNT, BP);

    // 2) gather -> QF bf16 (standalone: 12 VGPR, 0 LDS, max occupancy)
    gather_kernel<<<(N_Q + 3) / 4, 256, 0, stream>>>(C1h, s0, t0, CNT, BP, QF, N_Q);

    // 3) h1 = relu(QF + C2*s1 + t1) @ W1 + b1 (amode=2), BN finalize fused
    {
        dim3 g((N_Q + 127) / 128, C1N / 128);
        gemm_mfma<__bf16, 2><<<g, 256, 0, stream>>>(QF, C2b, s1, t1, W1t, b1, H1,
                                                    SUM2, SQ2, g1, be1, s2, t2,
                                                    1.f / N_Q, TK + 2, N_Q, C1N, C0);
    }

    // 4) h2 = relu(h1*s2 + t2) @ W2 + b2 (amode=1), BN finalize fused
    {
        dim3 g((N_Q + 127) / 128, C2N / 128);
        gemm_mfma<__bf16, 1><<<g, 256, 0, stream>>>(H1, nullptr, s2, t2, W2t, b2, H2,
                                                    SUM3, SQ3, g2, be2, s3, t3,
                                                    1.f / N_Q, TK + 3, N_Q, C2N, C1N);
    }

    // 5) out = relu(bn(h2))
    final_kernel<<<(N_Q * C2N / 8 + 255) / 256, 256, 0, stream>>>(H2, s3, t3, out, N_Q * C2N / 8);
}

// Round 10
// 223.632 us; speedup vs baseline: 1.7229x; 1.7229x over previous
//
#include <hip/hip_runtime.h>
#include <hip/hip_bf16.h>

// EdgeConvUp — N_REF=50000, N_Q=25000, E=400000, C=128, MLP 128/256/256. fp32 in/out.

#define N_REF 50000
#define N_Q   25000
#define E_CNT 400000
#define C0    128
#define C1N   256
#define C2N   256
#define BN_EPS 1e-5f
#define CAP   96        // bucket slots per query (mean deg 16, std 4; 96 = 20 sigma)
#define CNTS  16        // cnt stride (ints): one counter per 64B line (kills atomic line contention)
#define LDSS  72        // LDS row stride (64 + 8 pad) in bf16 elements
#define NB_BK 196       // bucket role blocks in mega1
#define NB_G1 391       // ceil(50000/128)
#define NB_G3 196       // ceil(25000/128)

typedef __bf16 bf16x8 __attribute__((ext_vector_type(8)));
typedef float  f32x4  __attribute__((ext_vector_type(4)));

// ---------- weight convert+transpose + zero padded counters ----------
__global__ __launch_bounds__(256) void convT_all(
    const float* __restrict__ Wf0, const float* __restrict__ Ws0,
    const float* __restrict__ W1,  const float* __restrict__ W2,
    __bf16* __restrict__ Wf0t, __bf16* __restrict__ Ws0t,
    __bf16* __restrict__ W1t,  __bf16* __restrict__ W2t,
    int* __restrict__ cnt)
{
    __shared__ float t[32][33];
    int b = blockIdx.x;
    for (int i = b * 256 + threadIdx.x; i < N_Q * CNTS; i += 128 * 256) cnt[i] = 0;
    const float* W; __bf16* O; int K, N, lb;
    if (b < 16)      { W = Wf0; O = Wf0t; K = 128; N = 128; lb = b; }
    else if (b < 32) { W = Ws0; O = Ws0t; K = 128; N = 128; lb = b - 16; }
    else if (b < 64) { W = W1;  O = W1t;  K = 128; N = 256; lb = b - 32; }
    else             { W = W2;  O = W2t;  K = 256; N = 256; lb = b - 64; }
    int nkb = K / 32;
    int bk = (lb % nkb) * 32, bn = (lb / nkb) * 32;
    int tx = threadIdx.x & 31, ty = threadIdx.x >> 5;
    #pragma unroll
    for (int i = 0; i < 32; i += 8)
        t[ty + i][tx] = W[(size_t)(bk + ty + i) * N + bn + tx];
    __syncthreads();
    #pragma unroll
    for (int i = 0; i < 32; i += 8)
        O[(size_t)(bn + ty + i) * K + bk + tx] = (__bf16)t[tx][ty + i];
}

__device__ inline void loadA8(const float* p, float* v) {
    float4 a0 = *(const float4*)p, a1 = *(const float4*)(p + 4);
    v[0] = a0.x; v[1] = a0.y; v[2] = a0.z; v[3] = a0.w;
    v[4] = a1.x; v[5] = a1.y; v[6] = a1.z; v[7] = a1.w;
}
__device__ inline void loadA8(const __bf16* p, float* v) {
    bf16x8 a = *(const bf16x8*)p;
    #pragma unroll
    for (int j = 0; j < 8; j++) v[j] = (float)a[j];
}

// ---------- GEMM body: 128x128 tile, BK=64, fused A-transform, bias, col-stat partials --
// AMODE: 0 plain; 1 relu(a*s+t); 2 relu(a + y*s + t). Output bf16.
// Per-block partials to distinct addresses (NO global atomics — round-9 lesson).
template <typename TA, int AMODE>
__device__ __forceinline__ void gemm_dev(
    __bf16* As, __bf16* Bs, float* sLDS, float* qLDS,
    const TA* __restrict__ A, const TA* __restrict__ A2,
    const float* __restrict__ sA, const float* __restrict__ tA,
    const __bf16* __restrict__ Bt, const float* __restrict__ bias,
    __bf16* __restrict__ Ch, float* __restrict__ part,
    int M, int N, int K, int bx, int by, int gridMx)
{
    const int bm = bx * 128, bn = by * 128;
    const int tid = threadIdx.x;
    const int wave = tid >> 6, lane = tid & 63;
    const int wm = wave >> 1, wn = wave & 1;
    const int m = lane & 15, quad = lane >> 4;
    f32x4 acc[4][4] = {};

    for (int kt = 0; kt < K; kt += 64) {
        #pragma unroll
        for (int cc = 0; cc < 4; cc++) {
            int c = tid + cc * 256;
            int row = c >> 3, kofs = (c & 7) * 8;
            int gr = bm + row;
            float va[8] = {0.f, 0.f, 0.f, 0.f, 0.f, 0.f, 0.f, 0.f};
            if (gr < M) {
                loadA8(A + (size_t)gr * K + kt + kofs, va);
                if (AMODE == 1) {
                    #pragma unroll
                    for (int j = 0; j < 8; j++)
                        va[j] = fmaxf(va[j] * sA[kt + kofs + j] + tA[kt + kofs + j], 0.f);
                } else if (AMODE == 2) {
                    float vy[8];
                    loadA8(A2 + (size_t)gr * K + kt + kofs, vy);
                    #pragma unroll
                    for (int j = 0; j < 8; j++)
                        va[j] = fmaxf(va[j] + vy[j] * sA[kt + kofs + j] + tA[kt + kofs + j], 0.f);
                }
            }
            bf16x8 av;
            #pragma unroll
            for (int j = 0; j < 8; j++) av[j] = (__bf16)va[j];
            *(bf16x8*)(As + row * LDSS + kofs) = av;
        }
        #pragma unroll
        for (int cc = 0; cc < 4; cc++) {
            int c = tid + cc * 256;
            int row = c >> 3, kofs = (c & 7) * 8;
            *(float4*)(Bs + row * LDSS + kofs) =
                *(const float4*)(Bt + (size_t)(bn + row) * K + kt + kofs);
        }
        __syncthreads();

        #pragma unroll
        for (int ks = 0; ks < 64; ks += 32) {
            bf16x8 af[4], bfr[4];
            #pragma unroll
            for (int mt = 0; mt < 4; mt++)
                af[mt] = *(const bf16x8*)(As + (wm * 64 + mt * 16 + m) * LDSS + ks + quad * 8);
            #pragma unroll
            for (int nt = 0; nt < 4; nt++)
                bfr[nt] = *(const bf16x8*)(Bs + (wn * 64 + nt * 16 + m) * LDSS + ks + quad * 8);
            #pragma unroll
            for (int mt = 0; mt < 4; mt++)
                #pragma unroll
                for (int nt = 0; nt < 4; nt++)
                    acc[mt][nt] = __builtin_amdgcn_mfma_f32_16x16x32_bf16(af[mt], bfr[nt], acc[mt][nt], 0, 0, 0);
        }
        __syncthreads();
    }

    if (tid < 128) { sLDS[tid] = 0.f; qLDS[tid] = 0.f; }
    __syncthreads();
    #pragma unroll
    for (int nt = 0; nt < 4; nt++) {
        int lcol = wn * 64 + nt * 16 + m;
        int col = bn + lcol;
        float bv = bias ? bias[col] : 0.f;
        float s_part = 0.f, q_part = 0.f;
        #pragma unroll
        for (int mt = 0; mt < 4; mt++) {
            #pragma unroll
            for (int r = 0; r < 4; r++) {
                int row = bm + wm * 64 + mt * 16 + quad * 4 + r;
                float v = acc[mt][nt][r] + bv;
                bool ok = row < M;
                s_part += ok ? v : 0.f;
                q_part += ok ? v * v : 0.f;
                if (ok) Ch[(size_t)row * N + col] = (__bf16)v;
            }
        }
        s_part += __shfl_xor(s_part, 16); s_part += __shfl_xor(s_part, 32);
        q_part += __shfl_xor(q_part, 16); q_part += __shfl_xor(q_part, 32);
        if (quad == 0) {
            atomicAdd(&sLDS[lcol], s_part);
            atomicAdd(&qLDS[lcol], q_part);
        }
    }
    __syncthreads();
    if (tid < 128) {
        size_t idx = ((size_t)by * gridMx + bx) * 256 + tid;
        part[idx] = sLDS[tid];
        part[idx + 128] = qLDS[tid];
    }
}

// ---------- bucket body: edge -> (q, slot), padded counters ----------
__device__ __forceinline__ void bucket_dev(
    const float* __restrict__ ref_bxyz, const float* __restrict__ query_bxyz,
    const int* __restrict__ e_ref, const int* __restrict__ e_query,
    int* __restrict__ cnt, int2* __restrict__ bp, int bkIdx)
{
    for (int e = bkIdx * 256 + threadIdx.x; e < E_CNT; e += NB_BK * 256) {
        int r = e_ref[e], q = e_query[e];
        float4 rp = *(const float4*)(ref_bxyz + (size_t)r * 4);
        float4 qp = *(const float4*)(query_bxyz + (size_t)q * 4);
        float dx = rp.y - qp.y, dy = rp.z - qp.z, dz = rp.w - qp.w;
        float wv = 1.f / (sqrtf(dx * dx + dy * dy + dz * dz) + 1e-8f);
        int pos = atomicAdd(&cnt[q * CNTS], 1);
        if (pos < CAP) bp[(size_t)q * CAP + pos] = make_int2(r, __float_as_int(wv));
    }
}

// ---------- mega1: bucket (196) + gemm1 (391) + gemm3 (196) ----------
__global__ __launch_bounds__(256) void mega1(
    const float* __restrict__ ref_feat, const float* __restrict__ query_feat,
    const __bf16* __restrict__ Wf0t, const __bf16* __restrict__ Ws0t,
    __bf16* __restrict__ C1h, __bf16* __restrict__ C2b,
    float* __restrict__ part1, float* __restrict__ part3,
    const float* __restrict__ ref_bxyz, const float* __restrict__ query_bxyz,
    const int* __restrict__ e_ref, const int* __restrict__ e_query,
    int* __restrict__ cnt, int2* __restrict__ bp)
{
    __shared__ __align__(16) __bf16 As[128 * LDSS];
    __shared__ __align__(16) __bf16 Bs[128 * LDSS];
    __shared__ float sLDS[128], qLDS[128];
    int b = blockIdx.x;
    if (b < NB_BK) {
        bucket_dev(ref_bxyz, query_bxyz, e_ref, e_query, cnt, bp, b);
    } else if (b < NB_BK + NB_G1) {
        gemm_dev<float, 0>(As, Bs, sLDS, qLDS, ref_feat, nullptr, nullptr, nullptr,
                           Wf0t, nullptr, C1h, part1, N_REF, C0, C0, b - NB_BK, 0, NB_G1);
    } else {
        gemm_dev<float, 0>(As, Bs, sLDS, qLDS, query_feat, nullptr, nullptr, nullptr,
                           Ws0t, nullptr, C2b, part3, N_Q, C0, C0, b - NB_BK - NB_G1, 0, NB_G3);
    }
}

// ---------- standalone GEMM (g4/g5) ----------
template <typename TA, int AMODE>
__global__ __launch_bounds__(256) void gemm_mfma(
    const TA* __restrict__ A, const TA* __restrict__ A2,
    const float* __restrict__ sA, const float* __restrict__ tA,
    const __bf16* __restrict__ Bt, const float* __restrict__ bias,
    __bf16* __restrict__ Ch, float* __restrict__ part,
    int M, int N, int K)
{
    __shared__ __align__(16) __bf16 As[128 * LDSS];
    __shared__ __align__(16) __bf16 Bs[128 * LDSS];
    __shared__ float sLDS[128], qLDS[128];
    gemm_dev<TA, AMODE>(As, Bs, sLDS, qLDS, A, A2, sA, tA, Bt, bias, Ch, part,
                        M, N, K, blockIdx.x, blockIdx.y, gridDim.x);
}

// ---------- dual bnfin for layer0 (feat, gridM=NB_G1) + layer1 (skip, gridM=NB_G3) ------
__global__ __launch_bounds__(64) void bnfin01_kernel(
    const float* __restrict__ p1, const float* __restrict__ p3,
    const float* __restrict__ gf0, const float* __restrict__ bf0,
    const float* __restrict__ gs0, const float* __restrict__ bs0,
    float* __restrict__ s0, float* __restrict__ t0,
    float* __restrict__ s1, float* __restrict__ t1)
{
    int c = blockIdx.x;
    const float* p; int gm; float invM; const float* g; const float* bb; float* so; float* to; int cl;
    if (c < 128) { p = p1; gm = NB_G1; invM = 1.f / N_REF; g = gf0; bb = bf0; so = s0; to = t0; cl = c; }
    else         { p = p3; gm = NB_G3; invM = 1.f / N_Q;   g = gs0; bb = bs0; so = s1; to = t1; cl = c - 128; }
    int lane = threadIdx.x;
    float s = 0.f, q = 0.f;
    for (int bm = lane; bm < gm; bm += 64) {
        s += p[bm * 256 + cl];
        q += p[bm * 256 + 128 + cl];
    }
    #pragma unroll
    for (int off = 32; off; off >>= 1) {
        s += __shfl_down(s, off, 64);
        q += __shfl_down(q, off, 64);
    }
    if (lane == 0) {
        float mu = s * invM;
        float var = q * invM - mu * mu;
        float sc = g[cl] * rsqrtf(var + BN_EPS);
        so[cl] = sc;
        to[cl] = bb[cl] - mu * sc;
    }
}

// ---------- bnfin for 256-col layers ----------
__global__ __launch_bounds__(64) void bnfin_kernel(
    const float* __restrict__ part, const float* __restrict__ g, const float* __restrict__ b,
    int gridM, float invM, float* __restrict__ s_out, float* __restrict__ t_out)
{
    int c = blockIdx.x;
    int bnIdx = c >> 7, cl = c & 127;
    const float* p = part + (size_t)bnIdx * gridM * 256;
    int lane = threadIdx.x;
    float s = 0.f, q = 0.f;
    for (int bm = lane; bm < gridM; bm += 64) {
        s += p[bm * 256 + cl];
        q += p[bm * 256 + 128 + cl];
    }
    #pragma unroll
    for (int off = 32; off; off >>= 1) {
        s += __shfl_down(s, off, 64);
        q += __shfl_down(q, off, 64);
    }
    if (lane == 0) {
        float mu = s * invM;
        float var = q * invM - mu * mu;
        float sc = g[c] * rsqrtf(var + BN_EPS);
        s_out[c] = sc;
        t_out[c] = b[c] - mu * sc;
    }
}

// ---------- gather (standalone, 0 LDS, high occupancy): wave/query, 4-edge ILP ----------
__global__ __launch_bounds__(256) void gather_kernel(
    const __bf16* __restrict__ C1h, const float* __restrict__ s0, const float* __restrict__ t0,
    const int* __restrict__ cnt, const int2* __restrict__ bp,
    __bf16* __restrict__ qf, int NQ)
{
    int q = blockIdx.x * 4 + (threadIdx.x >> 6);
    if (q >= NQ) return;
    int lane = threadIdx.x & 63;
    int sub = lane >> 4, m = lane & 15;
    int deg = min(cnt[q * CNTS], CAP);
    const int base = q * CAP;
    float acc[8] = {};
    float ws = 0.f;
    int i = sub;
    for (; i + 4 < deg; i += 8) {
        int2 p0 = bp[base + i], p1 = bp[base + i + 4];
        float w0 = __int_as_float(p0.y), w1 = __int_as_float(p1.y);
        bf16x8 v0 = *(const bf16x8*)(C1h + (size_t)p0.x * C0 + m * 8);
        bf16x8 v1 = *(const bf16x8*)(C1h + (size_t)p1.x * C0 + m * 8);
        ws += w0 + w1;
        #pragma unroll
        for (int j = 0; j < 8; j++) acc[j] += (float)v0[j] * w0 + (float)v1[j] * w1;
    }
    if (i < deg) {
        int2 p0 = bp[base + i];
        float w0 = __int_as_float(p0.y);
        bf16x8 v0 = *(const bf16x8*)(C1h + (size_t)p0.x * C0 + m * 8);
        ws += w0;
        #pragma unroll
        for (int j = 0; j < 8; j++) acc[j] += (float)v0[j] * w0;
    }
    ws += __shfl_xor(ws, 16); ws += __shfl_xor(ws, 32);
    #pragma unroll
    for (int j = 0; j < 8; j++) {
        acc[j] += __shfl_xor(acc[j], 16);
        acc[j] += __shfl_xor(acc[j], 32);
    }
    if (sub == 0) {
        float inv = (deg > 0) ? 1.f / ws : 0.f;
        float has = (deg > 0) ? 1.f : 0.f;
        bf16x8 o;
        #pragma unroll
        for (int j = 0; j < 8; j++) {
            int ch = m * 8 + j;
            o[j] = (__bf16)(acc[j] * inv * s0[ch] + t0[ch] * has);
        }
        *(bf16x8*)(qf + (size_t)q * C0 + m * 8) = o;
    }
}

// ---------- final: out = relu(bn(h2)), h2 bf16 -> out fp32, 8 elems/thread ----------
__global__ __launch_bounds__(256) void final_kernel(
    const __bf16* __restrict__ h2, const float* __restrict__ s, const float* __restrict__ t,
    float* __restrict__ out, int n8)
{
    int i8 = blockIdx.x * 256 + threadIdx.x;
    if (i8 >= n8) return;
    int base = i8 * 8;
    int c = base & 255;
    bf16x8 h = *(const bf16x8*)(h2 + base);
    float o[8];
    #pragma unroll
    for (int j = 0; j < 8; j++) {
        float v = (float)h[j] * s[c + j] + t[c + j];
        o[j] = v > 0.f ? v : 0.f;
    }
    *(float4*)(out + base)     = make_float4(o[0], o[1], o[2], o[3]);
    *(float4*)(out + base + 4) = make_float4(o[4], o[5], o[6], o[7]);
}

extern "C" void kernel_launch(void* const* d_in, const int* in_sizes, int n_in,
                              void* d_out, int out_size, void* d_ws, size_t ws_size,
                              hipStream_t stream)
{
    const float* ref_bxyz   = (const float*)d_in[0];
    const float* ref_feat   = (const float*)d_in[1];
    const float* query_bxyz = (const float*)d_in[2];
    const float* query_feat = (const float*)d_in[3];
    const int* e_ref   = (const int*)d_in[4];
    const int* e_query = (const int*)d_in[5];
    const float* Wf0 = (const float*)d_in[6];
    const float* gf0 = (const float*)d_in[7];
    const float* bf0 = (const float*)d_in[8];
    const float* Ws0 = (const float*)d_in[9];
    const float* gs0 = (const float*)d_in[10];
    const float* bs0 = (const float*)d_in[11];
    const float* W1  = (const float*)d_in[12];
    const float* b1  = (const float*)d_in[13];
    const float* g1  = (const float*)d_in[14];
    const float* be1 = (const float*)d_in[15];
    const float* W2  = (const float*)d_in[16];
    const float* b2  = (const float*)d_in[17];
    const float* g2  = (const float*)d_in[18];
    const float* be2 = (const float*)d_in[19];
    float* out = (float*)d_out;

    char* ws = (char*)d_ws;
    const size_t MB = 1024 * 1024;
    const size_t OFF_C1 = 0;              // C1 bf16 [50000,128] 12.8MB
    const size_t OFF_QF = 13 * MB;        // QF bf16 [25000,128] 6.4MB
    const size_t OFF_C2 = 20 * MB;        // C2 bf16 [25000,128] 6.4MB
    const size_t OFF_H1 = 27 * MB;        // h1 bf16 [25000,256] 12.8MB
    const size_t OFF_H2 = 40 * MB;        // h2 bf16 [25000,256] 12.8MB
    const size_t OFF_BP = 53 * MB;        // packed buckets int2 [25000*96] 19.2MB
    const size_t OFF_CNT = 73 * MB;       // padded cnt [25000*16] 1.6MB
    const size_t OFF_PT = 75 * MB;        // partial stats g1/g4/g5 1MB
    const size_t OFF_P3 = 76 * MB;        // partial stats g3 256KB
    const size_t OFF_ST = 77 * MB;        // s/t arrays
    const size_t OFF_BT = OFF_ST + 16384; // bf16 weights 256KB
    __bf16* C1h = (__bf16*)(ws + OFF_C1);
    __bf16* QF  = (__bf16*)(ws + OFF_QF);
    __bf16* C2b = (__bf16*)(ws + OFF_C2);
    __bf16* H1  = (__bf16*)(ws + OFF_H1);
    __bf16* H2  = (__bf16*)(ws + OFF_H2);
    int2*   BP  = (int2*)(ws + OFF_BP);
    int*    CNT = (int*)(ws + OFF_CNT);
    float*  PART = (float*)(ws + OFF_PT);
    float*  PART3 = (float*)(ws + OFF_P3);
    float* ST = (float*)(ws + OFF_ST);
    float *s0 = ST,        *t0 = ST + 256;
    float *s1 = ST + 512,  *t1 = ST + 768;
    float *s2 = ST + 1024, *t2 = ST + 1280;
    float *s3 = ST + 1536, *t3 = ST + 1792;
    __bf16* Wf0t = (__bf16*)(ws + OFF_BT);
    __bf16* Ws0t = Wf0t + 128 * 128;
    __bf16* W1t  = Ws0t + 128 * 128;
    __bf16* W2t  = W1t + 256 * 128;

    // 0) weight conversion + padded-cnt zeroing
    convT_all<<<128, 256, 0, stream>>>(Wf0, Ws0, W1, W2, Wf0t, Ws0t, W1t, W2t, CNT);

    // 1) fused: bucket + C1 = ref_feat@Wf0 + C2 = query_feat@Ws0 (per-block stat partials)
    mega1<<<NB_BK + NB_G1 + NB_G3, 256, 0, stream>>>(
        ref_feat, query_feat, Wf0t, Ws0t, C1h, C2b, PART, PART3,
        ref_bxyz, query_bxyz, e_ref, e_query, CNT, BP);
    bnfin01_kernel<<<256, 64, 0, stream>>>(PART, PART3, gf0, bf0, gs0, bs0, s0, t0, s1, t1);

    // 2) gather -> QF bf16 (standalone: low VGPR, 0 LDS, max occupancy)
    gather_kernel<<<(N_Q + 3) / 4, 256, 0, stream>>>(C1h, s0, t0, CNT, BP, QF, N_Q);

    // 3) h1 = relu(QF + C2*s1 + t1) @ W1 + b1 (amode=2), stats to PART
    {
        dim3 g((N_Q + 127) / 128, C1N / 128);
        gemm_mfma<__bf16, 2><<<g, 256, 0, stream>>>(QF, C2b, s1, t1,
                                                    W1t, b1, H1, PART, N_Q, C1N, C0);
        bnfin_kernel<<<C1N, 64, 0, stream>>>(PART, g1, be1, g.x, 1.f / N_Q, s2, t2);
    }

    // 4) h2 = relu(h1*s2 + t2) @ W2 + b2 (amode=1), stats to PART
    {
        dim3 g((N_Q + 127) / 128, C2N / 128);
        gemm_mfma<__bf16, 1><<<g, 256, 0, stream>>>(H1, nullptr, s2, t2,
                                                    W2t, b2, H2, PART, N_Q, C2N, C1N);
        bnfin_kernel<<<C2N, 64, 0, stream>>>(PART, g2, be2, g.x, 1.f / N_Q, s3, t3);
    }

    // 5) out = relu(bn(h2))
    final_kernel<<<(N_Q * C2N / 8 + 255) / 256, 256, 0, stream>>>(H2, s3, t3, out, N_Q * C2N / 8);
}